// Round 2
// baseline (219.877 us; speedup 1.0000x reference)
//
#include <hip/hip_runtime.h>

// Problem constants (from reference setup_inputs)
constexpr int B  = 32;
constexpr int C  = 3;
constexpr int H  = 512;
constexpr int W  = 512;
constexpr int HP = H / 4;    // 128 pooled rows
constexpr int WP = W / 4;    // 128 pooled cols
constexpr int NP = B * HP * WP;   // 524288 pooled pixels
constexpr int W4 = W / 4;    // 128 float4 per image row

// v3: slab-streaming decomposition.
// v2 post-mortem: 4x occupancy bought only +13% BW (2.45->2.77 TB/s) ->
// NOT latency-bound; the 528B scattered wave-segments cap the memory
// system at ~2.8 TB/s. Fix: block = one image x 8 pooled rows x FULL
// width -> per (channel,array) a contiguous 32-row 64KB slab, read as
// 1KB-contiguous wave-loads walking sequential 2KB rows. Full-width rows
// eliminate the left halo; only a 1-pooled-row top halo remains (+11%
// logical, L2/L3-hot from the neighbor block, helped by XCD swizzle).
// Thread (q,h) = pooled col q, image rows [32*br+16h, +16) -> computes 4
// complete pooled-diff pixels with zero cross-thread reduction.
constexpr int ROWS_PB    = 8;               // pooled rows per block
constexpr int BLK_PER_IMG = HP / ROWS_PB;   // 16
constexpr int NBLOCKS    = B * BLK_PER_IMG; // 512 -> 2 blocks/CU

__global__ __launch_bounds__(256, 2) void spatial_loss_fused(
        const float* __restrict__ x,
        const float* __restrict__ pred,
        float* __restrict__ out) {
    __shared__ float pt[ROWS_PB + 1][WP];   // 9 x 128 floats = 4.6 KB

    // Bijective XCD swizzle (512 % 8 == 0): consecutive logical blocks
    // (which share halo rows) land on the same XCD's L2.
    int orig = blockIdx.x;
    int blk  = (orig & 7) * (NBLOCKS / 8) + (orig >> 3);
    int b    = blk >> 4;          // image
    int br   = blk & 15;          // block-row within image
    int tid  = threadIdx.x;
    int q    = tid & 127;         // pooled column 0..127
    int h    = tid >> 7;          // row-half 0..1

    const float4* __restrict__ xb = (const float4*)x;
    const float4* __restrict__ pb = (const float4*)pred;

    // ---- Phase A: owned pooled-diff pixels (4 per thread, full rows) ----
    // Thread covers image rows row0..row0+15 at float4-column q.
    int row0 = br * 32 + h * 16;
    #pragma unroll
    for (int j = 0; j < 4; ++j) {           // pooled row 4h+j
        int base = (b * C * H + row0 + 4 * j) * W4 + q;
        float s0 = 0.0f, s1 = 0.0f;
        #pragma unroll
        for (int c = 0; c < C; ++c) {
            int a = base + c * H * W4;
            // 8 loads batched before any arithmetic -> 8 KB/wave in flight
            float4 x0 = xb[a];
            float4 x1 = xb[a + W4];
            float4 x2 = xb[a + 2 * W4];
            float4 x3 = xb[a + 3 * W4];
            float4 p0 = pb[a];
            float4 p1 = pb[a + W4];
            float4 p2 = pb[a + 2 * W4];
            float4 p3 = pb[a + 3 * W4];
            s0 += (x0.x - p0.x) + (x0.y - p0.y) + (x0.z - p0.z) + (x0.w - p0.w);
            s1 += (x1.x - p1.x) + (x1.y - p1.y) + (x1.z - p1.z) + (x1.w - p1.w);
            s0 += (x2.x - p2.x) + (x2.y - p2.y) + (x2.z - p2.z) + (x2.w - p2.w);
            s1 += (x3.x - p3.x) + (x3.y - p3.y) + (x3.z - p3.z) + (x3.w - p3.w);
        }
        pt[1 + 4 * h + j][q] = (s0 + s1) * (1.0f / 48.0f);
    }

    // ---- Top halo: pooled row br*8-1 (zero at image top border) ----
    if (tid < 128) {
        float s = 0.0f;
        if (br > 0) {
            int hr   = br * 32 - 4;
            int base = (b * C * H + hr) * W4 + tid;
            float s0 = 0.0f, s1 = 0.0f;
            #pragma unroll
            for (int c = 0; c < C; ++c) {
                int a = base + c * H * W4;
                float4 x0 = xb[a];
                float4 x1 = xb[a + W4];
                float4 x2 = xb[a + 2 * W4];
                float4 x3 = xb[a + 3 * W4];
                float4 p0 = pb[a];
                float4 p1 = pb[a + W4];
                float4 p2 = pb[a + 2 * W4];
                float4 p3 = pb[a + 3 * W4];
                s0 += (x0.x - p0.x) + (x0.y - p0.y) + (x0.z - p0.z) + (x0.w - p0.w);
                s1 += (x1.x - p1.x) + (x1.y - p1.y) + (x1.z - p1.z) + (x1.w - p1.w);
                s0 += (x2.x - p2.x) + (x2.y - p2.y) + (x2.z - p2.z) + (x2.w - p2.w);
                s1 += (x3.x - p3.x) + (x3.y - p3.y) + (x3.z - p3.z) + (x3.w - p3.w);
            }
            s = (s0 + s1) * (1.0f / 48.0f);
        }
        pt[0][tid] = s;
    }
    __syncthreads();

    // ---- Phase B: pair-counted gradient sum over owned 8x128 pixels ----
    // E*NP = 2*sum(adjacent-pair diffs^2) + sum(border p^2). Each block
    // counts the up-pair and left-pair of its OWNED pixels; full-width
    // rows mean the left neighbor is always in-tile (q==0 is the image
    // border: lf=0, weight 1 -> c^2 term automatically).
    float acc = 0.0f;
    #pragma unroll
    for (int j = 0; j < 4; ++j) {
        int row = 4 * h + j;              // 0..7 local pooled row
        int gy  = br * 8 + row;
        float c  = pt[row + 1][q];
        float up = pt[row][q];            // zero if gy==0 (halo filled 0)
        float lf = (q > 0) ? pt[row + 1][q - 1] : 0.0f;
        float dy = c - up;
        float dx = c - lf;
        float wy = (gy > 0) ? 2.0f : 1.0f;   // interior pair counted twice
        float wx = (q  > 0) ? 2.0f : 1.0f;
        acc += wy * dy * dy + wx * dx * dx;
        if (gy == HP - 1) acc += c * c;      // bottom border (d_down)
        if (q  == WP - 1) acc += c * c;      // right border (d_right)
    }

    // wave64 shuffle reduce -> LDS -> one pre-scaled atomicAdd per block
    #pragma unroll
    for (int off = 32; off > 0; off >>= 1)
        acc += __shfl_down(acc, off, 64);

    __shared__ float ws_red[4];
    int lane = tid & 63;
    int wid  = tid >> 6;
    if (lane == 0) ws_red[wid] = acc;
    __syncthreads();
    if (tid == 0) {
        float s = ws_red[0] + ws_red[1] + ws_red[2] + ws_red[3];
        atomicAdd(out, s * (1.0f / (float)NP));
    }
}

extern "C" void kernel_launch(void* const* d_in, const int* in_sizes, int n_in,
                              void* d_out, int out_size, void* d_ws, size_t ws_size,
                              hipStream_t stream) {
    const float* x    = (const float*)d_in[0];
    const float* pred = (const float*)d_in[1];
    float* out = (float*)d_out;

    // d_out is poisoned 0xAA before every launch — zero it (capture-safe).
    hipMemsetAsync(out, 0, sizeof(float), stream);

    spatial_loss_fused<<<NBLOCKS, 256, 0, stream>>>(x, pred, out);
}